// Round 10
// baseline (2315.913 us; speedup 1.0000x reference)
//
#include <hip/hip_runtime.h>
#include <hip/hip_fp16.h>
#include <hip/hip_cooperative_groups.h>
#include <stdint.h>

namespace cg = cooperative_groups;

typedef _Float16 f16;
typedef _Float16 f16x8 __attribute__((ext_vector_type(8)));
typedef float f32x4 __attribute__((ext_vector_type(4)));

#define NB 32768      // batch
#define LAYERS 6
#define AK 160        // HALF + COND
#define HID 1024

// async global->LDS, 16B per lane. LDS dest is wave-uniform base + lane*16.
__device__ __forceinline__ void async_copy16(const void* g, void* l) {
  __builtin_amdgcn_global_load_lds(
      (const __attribute__((address_space(1))) void*)g,
      (__attribute__((address_space(3))) void*)l, 16, 0, 0);
}

// ---------------------------------------------------------------------------
// 64x64 LDS-tiled transpose tile: W (K_ x N_ f32) -> Wt (N_ x K_ f16).
// Coalesced reads AND writes. Caller provides the LDS tile.
// ---------------------------------------------------------------------------
__device__ __forceinline__ void wtrans_tile(const float* __restrict__ W,
                                            f16* __restrict__ Wt,
                                            const int K_, const int N_,
                                            const int bx, const int by,
                                            const int bz, float (*t)[65])
{
  const long off = (long)bz * K_ * N_;
  const float* Wl = W + off;
  f16* Wtl = Wt + off;
  const int k0 = by * 64, n0 = bx * 64;
  const int tx = threadIdx.x & 63, ty4 = threadIdx.x >> 6;
#pragma unroll
  for (int r = ty4; r < 64; r += 4) {
    const int k = k0 + r;
    if (k < K_) t[r][tx] = Wl[(long)k * N_ + n0 + tx];
  }
  __syncthreads();
  const int k = k0 + tx;
  if (k < K_) {
#pragma unroll
    for (int r = ty4; r < 64; r += 4) {
      const int n = n0 + r;
      Wtl[(long)n * K_ + k] = (f16)t[tx][r];
    }
  }
}

// ---------------------------------------------------------------------------
// GEMM tile: C[128 x 1024 slice] = relu(A[128 x K] @ Wt^T + bias), f16 out.
// Exactly the R7/R9 plateau body (128x128 tile, BK=32, 4 waves, 64x64 wave
// tile, A/B LDS dbuf via global_load_lds, ONE barrier/k-step, XOR swizzle,
// 0 bank conflicts), operating on a caller-provided 32 KB LDS arena.
// Leading __syncthreads guards LDS reuse across consecutive tiles (odd-nK
// parity would otherwise let tile t+1's stage(0) race tile t's last reads).
// ---------------------------------------------------------------------------
__device__ void gemm_tile(const f16* __restrict__ A, const int K,
                          const f16* __restrict__ Wt,
                          const float* __restrict__ bias,
                          f16* __restrict__ C, const int t,
                          f16* __restrict__ sm)
{
  f16* AsB[2] = {sm, sm + 4096};
  f16* BsB[2] = {sm + 8192, sm + 12288};
  const int tid  = threadIdx.x;
  const int wave = tid >> 6;
  const int lane = tid & 63;
  const int c15  = lane & 15;
  const int quad = lane >> 4;
  const int wm = (wave & 1) * 64;
  const int wn = (wave >> 1) * 64;

  // XCD swizzle: 2048 tiles = 8 XCDs x 32 row-groups x 8 col-blocks
  const int x = t & 7, i = t >> 3;
  const long rowStart = (long)(x * 32 + (i >> 3)) * 128;
  const long colStart = (long)(i & 7) * 128;

  const f16* Ab = A  + rowStart * K;
  const f16* Bb = Wt + colStart * K;

  const int ra  = tid >> 2;
  const int kca = (((tid & 3) ^ ((ra >> 1) & 3))) * 8;

  f32x4 acc[4][4] = {};
  const int nK = K >> 5;

  auto stage = [&](int kt, int sel) {
    const long ko = (long)kt * 32;
    f16* as = AsB[sel];
    f16* bs = BsB[sel];
#pragma unroll
    for (int q = 0; q < 2; ++q)
      async_copy16(Ab + (long)(q * 64 + ra) * K + ko + kca,
                   as + (q * 256 + wave * 64) * 8);
#pragma unroll
    for (int q = 0; q < 2; ++q)
      async_copy16(Bb + (long)(q * 64 + ra) * K + ko + kca,
                   bs + (q * 256 + wave * 64) * 8);
  };

  __syncthreads();                 // previous tile's LDS reads fully retired
  stage(0, 0);
  for (int kt = 0; kt < nK; ++kt) {
    __syncthreads();               // drains stage(kt), issued one step ago
    if (kt + 1 < nK) stage(kt + 1, (kt + 1) & 1);
    const f16* as = AsB[kt & 1];
    const f16* bs = BsB[kt & 1];

    f16x8 a[4], bf[4];
#pragma unroll
    for (int mi = 0; mi < 4; ++mi) {
      const int R = wm + mi * 16 + c15;
      a[mi] = *(const f16x8*)&as[R * 32 + ((quad ^ ((R >> 1) & 3)) << 3)];
    }
#pragma unroll
    for (int ni = 0; ni < 4; ++ni) {
      const int R = wn + ni * 16 + c15;
      bf[ni] = *(const f16x8*)&bs[R * 32 + ((quad ^ ((R >> 1) & 3)) << 3)];
    }
#pragma unroll
    for (int mi = 0; mi < 4; ++mi)
#pragma unroll
      for (int ni = 0; ni < 4; ++ni)
        acc[mi][ni] = __builtin_amdgcn_mfma_f32_16x16x32_f16(
            a[mi], bf[ni], acc[mi][ni], 0, 0, 0);
  }

  // epilogue: bias + relu + f16 store. C/D layout: col=lane&15, row=quad*4+r
#pragma unroll
  for (int ni = 0; ni < 4; ++ni) {
    const long gn = colStart + wn + ni * 16 + c15;
    const float bv = bias[gn];
#pragma unroll
    for (int mi = 0; mi < 4; ++mi) {
#pragma unroll
      for (int r = 0; r < 4; ++r) {
        const long gm = rowStart + wm + mi * 16 + quad * 4 + r;
        float v = acc[mi][ni][r] + bv;
        v = fmaxf(v, 0.0f);
        C[gm * HID + gn] = (f16)v;
      }
    }
  }
}

// ---------------------------------------------------------------------------
// GEMM3 tile (N=64) + coupling epilogue. 64 rows per tile, 4 waves x 16x64.
// LDS dbuf 2 x 4 KB per operand, 1 barrier/step, XOR swizzle.
// s-col j and t-col j+32 share lane & reg slot -> no shuffles.
// Writes y to z (fp32, in d_out) and Anext[:, :32] (f16, next layer input).
// ---------------------------------------------------------------------------
__device__ void gemm3_tile(const f16* __restrict__ X2, const f16* __restrict__ W3t,
                           const float* __restrict__ b3, float* __restrict__ z,
                           float* __restrict__ log_det, f16* __restrict__ Anext,
                           const int maskoff, const int t, f16* __restrict__ sm)
{
  f16* AsB[2] = {sm, sm + 2048};
  f16* BsB[2] = {sm + 4096, sm + 6144};
  const int tid = threadIdx.x;
  const int wave = tid >> 6, lane = tid & 63;
  const int c15 = lane & 15, quad = lane >> 4;
  const int wm = wave * 16;
  const long rowStart = (long)t * 64;

  const f16* Ab = X2 + rowStart * HID;
  const int ra  = tid >> 2;                        // 0..63
  const int kca = (((tid & 3) ^ ((ra >> 1) & 3))) * 8;

  f32x4 acc[4] = {};

  auto stage = [&](int kt, int sel) {
    const long ko = (long)kt * 32;
    async_copy16(Ab + (long)ra * HID + ko + kca,
                 AsB[sel] + (wave * 64) * 8);
    async_copy16(W3t + (long)ra * HID + ko + kca,
                 BsB[sel] + (wave * 64) * 8);
  };

  __syncthreads();
  stage(0, 0);
  for (int kt = 0; kt < 32; ++kt) {
    __syncthreads();
    if (kt + 1 < 32) stage(kt + 1, (kt + 1) & 1);
    const f16* as = AsB[kt & 1];
    const f16* bs = BsB[kt & 1];

    const int Ra = wm + c15;
    f16x8 a = *(const f16x8*)&as[Ra * 32 + ((quad ^ ((Ra >> 1) & 3)) << 3)];
    f16x8 bf[4];
#pragma unroll
    for (int ni = 0; ni < 4; ++ni) {
      const int R = ni * 16 + c15;
      bf[ni] = *(const f16x8*)&bs[R * 32 + ((quad ^ ((R >> 1) & 3)) << 3)];
    }
#pragma unroll
    for (int ni = 0; ni < 4; ++ni)
      acc[ni] = __builtin_amdgcn_mfma_f32_16x16x32_f16(a, bf[ni], acc[ni], 0, 0, 0);
  }

  float sp[4] = {0.0f, 0.0f, 0.0f, 0.0f};
#pragma unroll
  for (int ni = 0; ni < 2; ++ni) {
    const int j = ni * 16 + c15;          // s-column 0..31
    const float bs = b3[j];
    const float bt = b3[32 + j];
#pragma unroll
    for (int r = 0; r < 4; ++r) {
      const long gm = rowStart + wm + quad * 4 + r;
      const float sv = acc[ni][r] + bs;
      const float e2 = __expf(2.0f * sv);            // tanh via exp
      const float s  = 1.0f - 2.0f / (e2 + 1.0f);
      const float tv = acc[ni + 2][r] + bt;
      const float m  = z[gm * 64 + maskoff + j];
      const float y  = fmaf(m, __expf(s), tv);
      z[gm * 64 + maskoff + j] = y;
      Anext[gm * AK + j] = (f16)y;   // next layer's unmasked input
      sp[r] += s;
    }
  }
#pragma unroll
  for (int r = 0; r < 4; ++r) {
    float v = sp[r];
    v += __shfl_xor(v, 1);
    v += __shfl_xor(v, 2);
    v += __shfl_xor(v, 4);
    v += __shfl_xor(v, 8);
    if (c15 == 0) {
      const long gm = rowStart + wm + quad * 4 + r;
      log_det[gm] += v;   // only this thread touches this row this layer
    }
  }
}

// ---------------------------------------------------------------------------
// Persistent cooperative kernel: all 19 former dispatches in one launch.
// Stages separated by grid.sync() (~1-2 us each) instead of launch gaps
// (~8-12 us each). One 32 KB LDS arena shared by all stages.
// ---------------------------------------------------------------------------
__global__ void __launch_bounds__(256, 4)
flow_all(const float* __restrict__ T, const float* __restrict__ cond,
         const float* __restrict__ W1, const float* __restrict__ W2,
         const float* __restrict__ W3, const float* __restrict__ b1,
         const float* __restrict__ b2, const float* __restrict__ b3,
         float* __restrict__ z, float* __restrict__ ld,
         f16* __restrict__ A, f16* __restrict__ X1, f16* __restrict__ X2,
         f16* __restrict__ W1t, f16* __restrict__ W2t, f16* __restrict__ W3t)
{
  __shared__ __align__(16) unsigned char smemraw[32768];
  f16* sm = (f16*)smemraw;
  cg::grid_group grid = cg::this_grid();

  // ---- prep: batch state + weight transposes ----
  {
    const int S1 = NB * 64;
    const int S2 = S1 + NB;
    const int S3 = S2 + NB * 32;
    const int S4 = S3 + NB * 128;
    for (int i = blockIdx.x * blockDim.x + threadIdx.x; i < S4;
         i += gridDim.x * blockDim.x) {
      if (i < S1) {
        z[i] = T[i];
      } else if (i < S2) {
        ld[i - S1] = 0.0f;
      } else if (i < S3) {
        int r = i - S2;
        int row = r >> 5, j = r & 31;
        A[(size_t)row * AK + j] = (f16)T[row * 64 + 32 + j];
      } else {
        int r = i - S3;
        int row = r >> 7, j = r & 127;
        A[(size_t)row * AK + 32 + j] = (f16)cond[r];
      }
    }
    // transpose tiles: W1 288 (16x3x6) + W2 1536 (16x16x6) + W3 96 (1x16x6)
    for (int tt = blockIdx.x; tt < 1920; tt += gridDim.x) {
      __syncthreads();
      float (*tile)[65] = (float(*)[65])smemraw;
      if (tt < 288) {
        wtrans_tile(W1, W1t, AK, 1024, tt % 16, (tt / 16) % 3, tt / 48, tile);
      } else if (tt < 1824) {
        const int l = tt - 288;
        wtrans_tile(W2, W2t, HID, 1024, l % 16, (l / 16) % 16, l / 256, tile);
      } else {
        const int l = tt - 1824;
        wtrans_tile(W3, W3t, HID, 64, 0, l % 16, l / 16, tile);
      }
    }
  }
  grid.sync();

  for (int l = 0; l < LAYERS; ++l) {
    const f16* w1 = W1t + (size_t)l * 1024 * AK;
    const f16* w2 = W2t + ((size_t)l << 20);
    const f16* w3 = W3t + (size_t)l * 64 * 1024;
    for (int t = blockIdx.x; t < 2048; t += gridDim.x)
      gemm_tile(A, AK, w1, b1 + l * 1024, X1, t, sm);
    grid.sync();
    for (int t = blockIdx.x; t < 2048; t += gridDim.x)
      gemm_tile(X1, HID, w2, b2 + l * 1024, X2, t, sm);
    grid.sync();
    const int maskoff = (l & 1) ? 32 : 0;
    for (int t = blockIdx.x; t < 512; t += gridDim.x)
      gemm3_tile(X2, w3, b3 + l * 64, z, ld, A, maskoff, t, sm);
    grid.sync();
  }
}

// ---------------------------------------------------------------------------
extern "C" void kernel_launch(void* const* d_in, const int* in_sizes, int n_in,
                              void* d_out, int out_size, void* d_ws, size_t ws_size,
                              hipStream_t stream) {
  (void)in_sizes; (void)n_in; (void)out_size; (void)ws_size;
  const float* T    = (const float*)d_in[0];
  const float* cond = (const float*)d_in[1];
  const float* W1   = (const float*)d_in[2];
  const float* b1   = (const float*)d_in[3];
  const float* W2   = (const float*)d_in[4];
  const float* b2   = (const float*)d_in[5];
  const float* W3   = (const float*)d_in[6];
  const float* b3   = (const float*)d_in[7];

  float* z  = (float*)d_out;                 // B x 64 working state = output
  float* ld = z + (size_t)NB * 64;           // B log_det

  f16* A   = (f16*)d_ws;                     // B x 160
  f16* X1  = A   + (size_t)NB * AK;          // B x 1024
  f16* X2  = X1  + (size_t)NB * HID;         // B x 1024
  f16* W1t = X2  + (size_t)NB * HID;         // 6 x 1024 x 160
  f16* W2t = W1t + (size_t)6 * 1024 * 160;   // 6 x 1024 x 1024
  f16* W3t = W2t + ((size_t)6 << 20);        // 6 x 64 x 1024

  // grid sized to guaranteed co-residency (cooperative launch requirement)
  int nb = 0;
  hipOccupancyMaxActiveBlocksPerMultiprocessor(&nb, flow_all, 256, 0);
  if (nb < 1) nb = 1;
  if (nb > 4) nb = 4;
  const int gblocks = 256 * nb;              // multiple of 8 -> XCD swizzle ok

  void* args[] = {
      (void*)&T, (void*)&cond, (void*)&W1, (void*)&W2, (void*)&W3,
      (void*)&b1, (void*)&b2, (void*)&b3,
      (void*)&z, (void*)&ld, (void*)&A, (void*)&X1, (void*)&X2,
      (void*)&W1t, (void*)&W2t, (void*)&W3t};
  hipLaunchCooperativeKernel(flow_all, dim3(gblocks), dim3(256), args, 0, stream);
}

// Round 11
// 950.962 us; speedup vs baseline: 2.4353x; 2.4353x over previous
//
#include <hip/hip_runtime.h>
#include <hip/hip_fp16.h>
#include <stdint.h>

typedef _Float16 f16;
typedef _Float16 f16x8 __attribute__((ext_vector_type(8)));
typedef float f32x4 __attribute__((ext_vector_type(4)));

#define NB 32768      // batch
#define LAYERS 6
#define AK 160        // HALF + COND
#define HID 1024

// async global->LDS, 16B per lane. LDS dest is wave-uniform base + lane*16.
__device__ __forceinline__ void async_copy16(const void* g, void* l) {
  __builtin_amdgcn_global_load_lds(
      (const __attribute__((address_space(1))) void*)g,
      (__attribute__((address_space(3))) void*)l, 16, 0, 0);
}

// ---------------------------------------------------------------------------
// Fused prep (R9): batch state + 3 weight transposes in one kernel.
// ---------------------------------------------------------------------------
__device__ __forceinline__ void wtrans_tile(const float* __restrict__ W,
                                            f16* __restrict__ Wt,
                                            const int K_, const int N_,
                                            const int bx, const int by,
                                            const int bz, float (*t)[65])
{
  const long off = (long)bz * K_ * N_;
  const float* Wl = W + off;
  f16* Wtl = Wt + off;
  const int k0 = by * 64, n0 = bx * 64;
  const int tx = threadIdx.x & 63, ty4 = threadIdx.x >> 6;
#pragma unroll
  for (int r = ty4; r < 64; r += 4) {
    const int k = k0 + r;
    if (k < K_) t[r][tx] = Wl[(long)k * N_ + n0 + tx];
  }
  __syncthreads();
  const int k = k0 + tx;
  if (k < K_) {
#pragma unroll
    for (int r = ty4; r < 64; r += 4) {
      const int n = n0 + r;
      Wtl[(long)n * K_ + k] = (f16)t[tx][r];
    }
  }
}

__global__ void prep_all(const float* __restrict__ T, const float* __restrict__ cond,
                         const float* __restrict__ W1, const float* __restrict__ W2,
                         const float* __restrict__ W3,
                         float* __restrict__ z, float* __restrict__ ld,
                         f16* __restrict__ A,
                         f16* __restrict__ W1t, f16* __restrict__ W2t,
                         f16* __restrict__ W3t)
{
  __shared__ float t[64][65];
  const int b = blockIdx.x;
  if (b < 2048) {
    const int S1 = NB * 64;
    const int S2 = S1 + NB;
    const int S3 = S2 + NB * 32;
    const int S4 = S3 + NB * 128;
    for (int i = b * blockDim.x + threadIdx.x; i < S4; i += 2048 * blockDim.x) {
      if (i < S1) {
        z[i] = T[i];
      } else if (i < S2) {
        ld[i - S1] = 0.0f;
      } else if (i < S3) {
        int r = i - S2;
        int row = r >> 5, j = r & 31;
        A[(size_t)row * AK + j] = (f16)T[row * 64 + 32 + j];
      } else {
        int r = i - S3;
        int row = r >> 7, j = r & 127;
        A[(size_t)row * AK + 32 + j] = (f16)cond[r];
      }
    }
  } else if (b < 2048 + 288) {
    const int l = b - 2048;                      // 16 x 3 x 6
    wtrans_tile(W1, W1t, AK, 1024, l % 16, (l / 16) % 3, l / 48, t);
  } else if (b < 2048 + 288 + 1536) {
    const int l = b - (2048 + 288);              // 16 x 16 x 6
    wtrans_tile(W2, W2t, HID, 1024, l % 16, (l / 16) % 16, l / 256, t);
  } else {
    const int l = b - (2048 + 288 + 1536);       // 1 x 16 x 6
    wtrans_tile(W3, W3t, HID, 64, 0, l % 16, l / 16, t);
  }
}

// ---------------------------------------------------------------------------
// GEMM1 (K=160): R9 single-shot version (entire tiles in 80 KB LDS, one
// barrier, 80 straight MFMA). Unchanged.
// ---------------------------------------------------------------------------
__global__ __launch_bounds__(256, 2)
void gemm1_full(const f16* __restrict__ A,
                const f16* __restrict__ Wt,       // 1024 x 160
                const float* __restrict__ bias,
                f16* __restrict__ C)
{
  __shared__ __align__(16) f16 As[128 * 160];     // 40 KB
  __shared__ __align__(16) f16 Bs[128 * 160];     // 40 KB
  const int tid  = threadIdx.x;
  const int lane = tid & 63;
  const int wave = tid >> 6;
  const int c15  = lane & 15;
  const int quad = lane >> 4;
  const int wm = (wave & 1) * 64;
  const int wn = (wave >> 1) * 64;

  const int b = blockIdx.x;
  const int x = b & 7, i = b >> 3;
  const long rowStart = (long)(x * 32 + (i >> 3)) * 128;
  const long colStart = (long)(i & 7) * 128;

  const f16* Ab = A  + rowStart * AK;
  const f16* Bb = Wt + colStart * AK;

#pragma unroll
  for (int it = 0; it < 10; ++it) {
    const int f = it * 256 + tid;
    const int row = f / 20;
    const int ch  = f - row * 20;
    const int chs = ch ^ ((row >> 1) & 3);
    async_copy16(Ab + (long)row * AK + chs * 8, &As[0] + (long)f * 8);
    async_copy16(Bb + (long)row * AK + chs * 8, &Bs[0] + (long)f * 8);
  }
  __syncthreads();

  f32x4 acc[4][4] = {};
#pragma unroll
  for (int kt = 0; kt < 5; ++kt) {
    f16x8 a[4], bf[4];
#pragma unroll
    for (int mi = 0; mi < 4; ++mi) {
      const int R = wm + mi * 16 + c15;
      a[mi] = *(const f16x8*)&As[(R * 20 + kt * 4 + (quad ^ ((R >> 1) & 3))) * 8];
    }
#pragma unroll
    for (int ni = 0; ni < 4; ++ni) {
      const int R = wn + ni * 16 + c15;
      bf[ni] = *(const f16x8*)&Bs[(R * 20 + kt * 4 + (quad ^ ((R >> 1) & 3))) * 8];
    }
#pragma unroll
    for (int mi = 0; mi < 4; ++mi)
#pragma unroll
      for (int ni = 0; ni < 4; ++ni)
        acc[mi][ni] = __builtin_amdgcn_mfma_f32_16x16x32_f16(
            a[mi], bf[ni], acc[mi][ni], 0, 0, 0);
  }

#pragma unroll
  for (int ni = 0; ni < 4; ++ni) {
    const long gn = colStart + wn + ni * 16 + c15;
    const float bv = bias[gn];
#pragma unroll
    for (int mi = 0; mi < 4; ++mi) {
#pragma unroll
      for (int r = 0; r < 4; ++r) {
        const long gm = rowStart + wm + mi * 16 + quad * 4 + r;
        float v = acc[mi][ni][r] + bv;
        v = fmaxf(v, 0.0f);
        C[gm * HID + gn] = (f16)v;
      }
    }
  }
}

// ---------------------------------------------------------------------------
// GEMM2 (K=1024) — R11: producer-consumer wave specialization.
// 320 threads: waves 0-3 = consumers (2x2 grid of 64x64 wave tiles, same
// validated fragment mapping + XOR swizzle), wave 4 = producer.
// LDS = 3-slot ring (3 x (8KB A + 8KB B) = 48 KB -> 3 blocks/CU, 15 waves).
// NO s_barrier in the K-loop -> the compiler's vmcnt(0)-before-barrier drain
// (the documented ~46% stall of the m97 structure) cannot occur.
// Producer runs one slot ahead; publishes slot kt-1 with inline-asm
// `s_waitcnt vmcnt(16)` (16 newer loads still in flight — AITER pattern,
// m135-verified) + LDS flag. Slot reuse gated on consumed[slot] (4 inc/gen).
// Consumers poll the flag (lgkm-only), ds_read_b128 + 16 MFMA, never vmcnt.
// ---------------------------------------------------------------------------
__global__ __launch_bounds__(320)
void gemm2_pc(const f16* __restrict__ A,
              const f16* __restrict__ Wt,        // 1024 x 1024
              const float* __restrict__ bias,
              f16* __restrict__ C)
{
  __shared__ __align__(16) f16 ring[3][8192];    // slot: [0..4096)=A, [4096..)=B
  __shared__ int flag[3];                         // slot holds data for kt: flag==kt+1
  __shared__ int consumed[3];                     // 4 increments per generation

  const int tid  = threadIdx.x;
  const int wave = tid >> 6;
  const int lane = tid & 63;

  const int b = blockIdx.x;
  const int x = b & 7, i = b >> 3;
  const long rowStart = (long)(x * 32 + (i >> 3)) * 128;
  const long colStart = (long)(i & 7) * 128;
  const int K = HID, nK = 32;

  if (tid < 3) { flag[tid] = 0; consumed[tid] = 0; }
  __syncthreads();   // no loads in flight; drain is free

  if (wave == 4) {
    // ------------------------- producer -------------------------
    const f16* Ab = A  + rowStart * K;
    const f16* Bb = Wt + colStart * K;
    // issue i covers rows [i*16, i*16+16): phys chunk f = i*64+lane,
    // row = f>>2, logical k-chunk = (lane&3)^((row>>1)&3)  (XOR swizzle)
    const int rowA = lane >> 2;                       // + i*16
    const int kc   = ((lane & 3) ^ ((rowA >> 1) & 3)) * 8;  // NOTE: row parity
    // careful: swizzle depends on full row = i*16 + rowA; (row>>1)&3 differs
    // per issue i only via bits 3..4 of row -> recompute inside the loop.
    for (int kt = 0; kt < nK; ++kt) {
      const int slot = kt % 3;
      if (kt >= 3) {
        const int want = 4 * (kt / 3);
        while (__hip_atomic_load(&consumed[slot], __ATOMIC_RELAXED,
                                 __HIP_MEMORY_SCOPE_WORKGROUP) < want)
          __builtin_amdgcn_s_sleep(1);
      }
      const long ko = (long)kt * 32;
      f16* as = &ring[slot][0];
      f16* bs = &ring[slot][4096];
#pragma unroll
      for (int is = 0; is < 8; ++is) {
        const int row = is * 16 + rowA;
        const int kcs = ((lane & 3) ^ ((row >> 1) & 3)) * 8;
        async_copy16(Ab + (long)row * K + ko + kcs, as + (is * 64) * 8);
        async_copy16(Bb + (long)row * K + ko + kcs, bs + (is * 64) * 8);
      }
      if (kt >= 1) {
        asm volatile("s_waitcnt vmcnt(16)" ::: "memory");  // kt-1's 16 done
        __hip_atomic_store(&flag[(kt - 1) % 3], kt, __ATOMIC_RELEASE,
                           __HIP_MEMORY_SCOPE_WORKGROUP);
      }
    }
    asm volatile("s_waitcnt vmcnt(0)" ::: "memory");
    __hip_atomic_store(&flag[(nK - 1) % 3], nK, __ATOMIC_RELEASE,
                       __HIP_MEMORY_SCOPE_WORKGROUP);
    (void)kc;
    return;
  }

  // ------------------------- consumers -------------------------
  const int c15  = lane & 15;
  const int quad = lane >> 4;
  const int wm = (wave & 1) * 64;
  const int wn = (wave >> 1) * 64;

  f32x4 acc[4][4] = {};

  for (int kt = 0; kt < nK; ++kt) {
    const int slot = kt % 3;
    while (__hip_atomic_load(&flag[slot], __ATOMIC_ACQUIRE,
                             __HIP_MEMORY_SCOPE_WORKGROUP) < kt + 1)
      __builtin_amdgcn_s_sleep(1);
    const f16* as = &ring[slot][0];
    const f16* bs = &ring[slot][4096];

    f16x8 a[4], bf[4];
#pragma unroll
    for (int mi = 0; mi < 4; ++mi) {
      const int R = wm + mi * 16 + c15;
      a[mi] = *(const f16x8*)&as[R * 32 + ((quad ^ ((R >> 1) & 3)) << 3)];
    }
#pragma unroll
    for (int ni = 0; ni < 4; ++ni) {
      const int R = wn + ni * 16 + c15;
      bf[ni] = *(const f16x8*)&bs[R * 32 + ((quad ^ ((R >> 1) & 3)) << 3)];
    }
#pragma unroll
    for (int mi = 0; mi < 4; ++mi)
#pragma unroll
      for (int ni = 0; ni < 4; ++ni)
        acc[mi][ni] = __builtin_amdgcn_mfma_f32_16x16x32_f16(
            a[mi], bf[ni], acc[mi][ni], 0, 0, 0);

    if (lane == 0)
      __hip_atomic_fetch_add(&consumed[slot], 1, __ATOMIC_RELEASE,
                             __HIP_MEMORY_SCOPE_WORKGROUP);
  }

  // epilogue: bias + relu + f16 store. C/D layout: col=lane&15, row=quad*4+r
#pragma unroll
  for (int ni = 0; ni < 4; ++ni) {
    const long gn = colStart + wn + ni * 16 + c15;
    const float bv = bias[gn];
#pragma unroll
    for (int mi = 0; mi < 4; ++mi) {
#pragma unroll
      for (int r = 0; r < 4; ++r) {
        const long gm = rowStart + wm + mi * 16 + quad * 4 + r;
        float v = acc[mi][ni][r] + bv;
        v = fmaxf(v, 0.0f);
        C[gm * HID + gn] = (f16)v;
      }
    }
  }
}

// ---------------------------------------------------------------------------
// GEMM3 (N=64) + coupling epilogue. R9 version unchanged (BM=64, grid 512,
// 2 blocks/CU, 1 barrier/step dbuf, XOR swizzle).
// ---------------------------------------------------------------------------
__global__ __launch_bounds__(256, 4)
void gemm3_coupling(const f16* __restrict__ X2, const f16* __restrict__ W3t,
                    const float* __restrict__ b3, float* __restrict__ z,
                    float* __restrict__ log_det, f16* __restrict__ Anext,
                    const int maskoff)
{
  __shared__ __align__(16) f16 As[2][64 * 32];
  __shared__ __align__(16) f16 Bs[2][64 * 32];
  const int tid = threadIdx.x;
  const int wave = tid >> 6, lane = tid & 63;
  const int c15 = lane & 15, quad = lane >> 4;
  const int wm = wave * 16;
  const long rowStart = (long)blockIdx.x * 64;

  const f16* Ab = X2 + rowStart * HID;
  const int ra  = tid >> 2;                        // 0..63
  const int kca = (((tid & 3) ^ ((ra >> 1) & 3))) * 8;

  f32x4 acc[4] = {};

  auto stage = [&](int kt, int sel) {
    const long ko = (long)kt * 32;
    async_copy16(Ab + (long)ra * HID + ko + kca,
                 &As[sel][0] + (wave * 64) * 8);
    async_copy16(W3t + (long)ra * HID + ko + kca,
                 &Bs[sel][0] + (wave * 64) * 8);
  };

  stage(0, 0);
  for (int kt = 0; kt < 32; ++kt) {
    __syncthreads();
    if (kt + 1 < 32) stage(kt + 1, (kt + 1) & 1);
    const f16* as = &As[kt & 1][0];
    const f16* bs = &Bs[kt & 1][0];

    const int Ra = wm + c15;
    f16x8 a = *(const f16x8*)&as[Ra * 32 + ((quad ^ ((Ra >> 1) & 3)) << 3)];
    f16x8 bf[4];
#pragma unroll
    for (int ni = 0; ni < 4; ++ni) {
      const int R = ni * 16 + c15;
      bf[ni] = *(const f16x8*)&bs[R * 32 + ((quad ^ ((R >> 1) & 3)) << 3)];
    }
#pragma unroll
    for (int ni = 0; ni < 4; ++ni)
      acc[ni] = __builtin_amdgcn_mfma_f32_16x16x32_f16(a, bf[ni], acc[ni], 0, 0, 0);
  }

  float sp[4] = {0.0f, 0.0f, 0.0f, 0.0f};
#pragma unroll
  for (int ni = 0; ni < 2; ++ni) {
    const int j = ni * 16 + c15;          // s-column 0..31
    const float bs = b3[j];
    const float bt = b3[32 + j];
#pragma unroll
    for (int r = 0; r < 4; ++r) {
      const long gm = rowStart + wm + quad * 4 + r;
      const float sv = acc[ni][r] + bs;
      const float e2 = __expf(2.0f * sv);            // tanh via exp
      const float s  = 1.0f - 2.0f / (e2 + 1.0f);
      const float tv = acc[ni + 2][r] + bt;
      const float m  = z[gm * 64 + maskoff + j];
      const float y  = fmaf(m, __expf(s), tv);
      z[gm * 64 + maskoff + j] = y;
      Anext[gm * AK + j] = (f16)y;   // next layer's unmasked input
      sp[r] += s;
    }
  }
#pragma unroll
  for (int r = 0; r < 4; ++r) {
    float v = sp[r];
    v += __shfl_xor(v, 1);
    v += __shfl_xor(v, 2);
    v += __shfl_xor(v, 4);
    v += __shfl_xor(v, 8);
    if (c15 == 0) {
      const long gm = rowStart + wm + quad * 4 + r;
      log_det[gm] += v;   // only this thread touches this row this layer
    }
  }
}

// ---------------------------------------------------------------------------
extern "C" void kernel_launch(void* const* d_in, const int* in_sizes, int n_in,
                              void* d_out, int out_size, void* d_ws, size_t ws_size,
                              hipStream_t stream) {
  (void)in_sizes; (void)n_in; (void)out_size; (void)ws_size;
  const float* T    = (const float*)d_in[0];
  const float* cond = (const float*)d_in[1];
  const float* W1   = (const float*)d_in[2];
  const float* b1   = (const float*)d_in[3];
  const float* W2   = (const float*)d_in[4];
  const float* b2   = (const float*)d_in[5];
  const float* W3   = (const float*)d_in[6];
  const float* b3   = (const float*)d_in[7];

  float* z  = (float*)d_out;                 // B x 64 working state = output
  float* ld = z + (size_t)NB * 64;           // B log_det

  f16* A   = (f16*)d_ws;                     // B x 160
  f16* X1  = A   + (size_t)NB * AK;          // B x 1024
  f16* X2  = X1  + (size_t)NB * HID;         // B x 1024
  f16* W1t = X2  + (size_t)NB * HID;         // 6 x 1024 x 160
  f16* W2t = W1t + (size_t)6 * 1024 * 160;   // 6 x 1024 x 1024
  f16* W3t = W2t + ((size_t)6 << 20);        // 6 x 64 x 1024

  prep_all<<<3968, 256, 0, stream>>>(T, cond, W1, W2, W3,
                                     z, ld, A, W1t, W2t, W3t);

  const int g12 = (NB / 128) * (HID / 128);  // 2048 blocks
  for (int l = 0; l < LAYERS; ++l) {
    gemm1_full<<<g12, 256, 0, stream>>>(A, W1t + (size_t)l * 1024 * AK,
                                        b1 + l * 1024, X1);
    gemm2_pc<<<g12, 320, 0, stream>>>(X1, W2t + ((size_t)l << 20),
                                      b2 + l * 1024, X2);
    const int maskoff = (l & 1) ? 32 : 0;
    gemm3_coupling<<<NB / 64, 256, 0, stream>>>(X2, W3t + (size_t)l * 64 * 1024,
                                                b3 + l * 64, z, ld, A, maskoff);
  }
}

// Round 12
// 885.496 us; speedup vs baseline: 2.6154x; 1.0739x over previous
//
#include <hip/hip_runtime.h>
#include <hip/hip_fp16.h>
#include <stdint.h>

typedef _Float16 f16;
typedef _Float16 f16x8 __attribute__((ext_vector_type(8)));
typedef float f32x4 __attribute__((ext_vector_type(4)));

#define NB 32768      // batch
#define LAYERS 6
#define AK 160        // HALF + COND
#define HID 1024

// async global->LDS, 16B per lane. LDS dest is wave-uniform base + lane*16.
__device__ __forceinline__ void async_copy16(const void* g, void* l) {
  __builtin_amdgcn_global_load_lds(
      (const __attribute__((address_space(1))) void*)g,
      (__attribute__((address_space(3))) void*)l, 16, 0, 0);
}

// ---------------------------------------------------------------------------
// Fused prep: batch state + 3 weight transposes in one kernel.
// ---------------------------------------------------------------------------
__device__ __forceinline__ void wtrans_tile(const float* __restrict__ W,
                                            f16* __restrict__ Wt,
                                            const int K_, const int N_,
                                            const int bx, const int by,
                                            const int bz, float (*t)[65])
{
  const long off = (long)bz * K_ * N_;
  const float* Wl = W + off;
  f16* Wtl = Wt + off;
  const int k0 = by * 64, n0 = bx * 64;
  const int tx = threadIdx.x & 63, ty4 = threadIdx.x >> 6;
#pragma unroll
  for (int r = ty4; r < 64; r += 4) {
    const int k = k0 + r;
    if (k < K_) t[r][tx] = Wl[(long)k * N_ + n0 + tx];
  }
  __syncthreads();
  const int k = k0 + tx;
  if (k < K_) {
#pragma unroll
    for (int r = ty4; r < 64; r += 4) {
      const int n = n0 + r;
      Wtl[(long)n * K_ + k] = (f16)t[tx][r];
    }
  }
}

__global__ void prep_all(const float* __restrict__ T, const float* __restrict__ cond,
                         const float* __restrict__ W1, const float* __restrict__ W2,
                         const float* __restrict__ W3,
                         float* __restrict__ z, float* __restrict__ ld,
                         f16* __restrict__ A,
                         f16* __restrict__ W1t, f16* __restrict__ W2t,
                         f16* __restrict__ W3t)
{
  __shared__ float t[64][65];
  const int b = blockIdx.x;
  if (b < 2048) {
    const int S1 = NB * 64;
    const int S2 = S1 + NB;
    const int S3 = S2 + NB * 32;
    const int S4 = S3 + NB * 128;
    for (int i = b * blockDim.x + threadIdx.x; i < S4; i += 2048 * blockDim.x) {
      if (i < S1) {
        z[i] = T[i];
      } else if (i < S2) {
        ld[i - S1] = 0.0f;
      } else if (i < S3) {
        int r = i - S2;
        int row = r >> 5, j = r & 31;
        A[(size_t)row * AK + j] = (f16)T[row * 64 + 32 + j];
      } else {
        int r = i - S3;
        int row = r >> 7, j = r & 127;
        A[(size_t)row * AK + 32 + j] = (f16)cond[r];
      }
    }
  } else if (b < 2048 + 288) {
    const int l = b - 2048;                      // 16 x 3 x 6
    wtrans_tile(W1, W1t, AK, 1024, l % 16, (l / 16) % 3, l / 48, t);
  } else if (b < 2048 + 288 + 1536) {
    const int l = b - (2048 + 288);              // 16 x 16 x 6
    wtrans_tile(W2, W2t, HID, 1024, l % 16, (l / 16) % 16, l / 256, t);
  } else {
    const int l = b - (2048 + 288 + 1536);       // 1 x 16 x 6
    wtrans_tile(W3, W3t, HID, 64, 0, l % 16, l / 16, t);
  }
}

// ---------------------------------------------------------------------------
// GEMM1 (K=160), layer 0 only: entire tiles in 80 KB LDS, one barrier,
// 80 straight MFMA. Validated R8/R9 body, unchanged.
// ---------------------------------------------------------------------------
__global__ __launch_bounds__(256, 2)
void gemm1_full(const f16* __restrict__ A,
                const f16* __restrict__ Wt,       // 1024 x 160
                const float* __restrict__ bias,
                f16* __restrict__ C)
{
  __shared__ __align__(16) f16 As[128 * 160];     // 40 KB
  __shared__ __align__(16) f16 Bs[128 * 160];     // 40 KB
  const int tid  = threadIdx.x;
  const int lane = tid & 63;
  const int wave = tid >> 6;
  const int c15  = lane & 15;
  const int quad = lane >> 4;
  const int wm = (wave & 1) * 64;
  const int wn = (wave >> 1) * 64;

  const int b = blockIdx.x;
  const int x = b & 7, i = b >> 3;
  const long rowStart = (long)(x * 32 + (i >> 3)) * 128;
  const long colStart = (long)(i & 7) * 128;

  const f16* Ab = A  + rowStart * AK;
  const f16* Bb = Wt + colStart * AK;

#pragma unroll
  for (int it = 0; it < 10; ++it) {
    const int f = it * 256 + tid;
    const int row = f / 20;
    const int ch  = f - row * 20;
    const int chs = ch ^ ((row >> 1) & 3);
    async_copy16(Ab + (long)row * AK + chs * 8, &As[0] + (long)f * 8);
    async_copy16(Bb + (long)row * AK + chs * 8, &Bs[0] + (long)f * 8);
  }
  __syncthreads();

  f32x4 acc[4][4] = {};
#pragma unroll
  for (int kt = 0; kt < 5; ++kt) {
    f16x8 a[4], bf[4];
#pragma unroll
    for (int mi = 0; mi < 4; ++mi) {
      const int R = wm + mi * 16 + c15;
      a[mi] = *(const f16x8*)&As[(R * 20 + kt * 4 + (quad ^ ((R >> 1) & 3))) * 8];
    }
#pragma unroll
    for (int ni = 0; ni < 4; ++ni) {
      const int R = wn + ni * 16 + c15;
      bf[ni] = *(const f16x8*)&Bs[(R * 20 + kt * 4 + (quad ^ ((R >> 1) & 3))) * 8];
    }
#pragma unroll
    for (int mi = 0; mi < 4; ++mi)
#pragma unroll
      for (int ni = 0; ni < 4; ++ni)
        acc[mi][ni] = __builtin_amdgcn_mfma_f32_16x16x32_f16(
            a[mi], bf[ni], acc[mi][ni], 0, 0, 0);
  }

#pragma unroll
  for (int ni = 0; ni < 4; ++ni) {
    const long gn = colStart + wn + ni * 16 + c15;
    const float bv = bias[gn];
#pragma unroll
    for (int mi = 0; mi < 4; ++mi) {
#pragma unroll
      for (int r = 0; r < 4; ++r) {
        const long gm = rowStart + wm + mi * 16 + quad * 4 + r;
        float v = acc[mi][ni][r] + bv;
        v = fmaxf(v, 0.0f);
        C[gm * HID + gn] = (f16)v;
      }
    }
  }
}

// ---------------------------------------------------------------------------
// GEMM2 (K=1024): the R7/R9 plateau kernel, unchanged (structural ceiling
// ~88 us verified across R3/R7/R9; all restructurings R4/R5/R6/R10/R11 lost).
// ---------------------------------------------------------------------------
__global__ __launch_bounds__(256, 3)
void gemm12(const f16* __restrict__ A, const int K,
            const f16* __restrict__ Wt,
            const float* __restrict__ bias,
            f16* __restrict__ C)
{
  __shared__ __align__(16) f16 As[2][128 * 32];
  __shared__ __align__(16) f16 Bs[2][128 * 32];
  const int tid  = threadIdx.x;
  const int wave = tid >> 6;
  const int lane = tid & 63;
  const int c15  = lane & 15;
  const int quad = lane >> 4;
  const int wm = (wave & 1) * 64;
  const int wn = (wave >> 1) * 64;

  const int b = blockIdx.x;
  const int x = b & 7, i = b >> 3;
  const long rowStart = (long)(x * 32 + (i >> 3)) * 128;
  const long colStart = (long)(i & 7) * 128;

  const f16* Ab = A  + rowStart * K;
  const f16* Bb = Wt + colStart * K;

  const int ra  = tid >> 2;
  const int kca = (((tid & 3) ^ ((ra >> 1) & 3))) * 8;

  f32x4 acc[4][4] = {};
  const int nK = K >> 5;

  auto stage = [&](int kt, int sel) {
    const long ko = (long)kt * 32;
    f16* as = &As[sel][0];
    f16* bs = &Bs[sel][0];
#pragma unroll
    for (int q = 0; q < 2; ++q)
      async_copy16(Ab + (long)(q * 64 + ra) * K + ko + kca,
                   as + (q * 256 + wave * 64) * 8);
#pragma unroll
    for (int q = 0; q < 2; ++q)
      async_copy16(Bb + (long)(q * 64 + ra) * K + ko + kca,
                   bs + (q * 256 + wave * 64) * 8);
  };

  stage(0, 0);
  for (int kt = 0; kt < nK; ++kt) {
    __syncthreads();
    if (kt + 1 < nK) stage(kt + 1, (kt + 1) & 1);
    const f16* as = &As[kt & 1][0];
    const f16* bs = &Bs[kt & 1][0];

    f16x8 a[4], bf[4];
#pragma unroll
    for (int mi = 0; mi < 4; ++mi) {
      const int R = wm + mi * 16 + c15;
      a[mi] = *(const f16x8*)&as[R * 32 + ((quad ^ ((R >> 1) & 3)) << 3)];
    }
#pragma unroll
    for (int ni = 0; ni < 4; ++ni) {
      const int R = wn + ni * 16 + c15;
      bf[ni] = *(const f16x8*)&bs[R * 32 + ((quad ^ ((R >> 1) & 3)) << 3)];
    }
#pragma unroll
    for (int mi = 0; mi < 4; ++mi)
#pragma unroll
      for (int ni = 0; ni < 4; ++ni)
        acc[mi][ni] = __builtin_amdgcn_mfma_f32_16x16x32_f16(
            a[mi], bf[ni], acc[mi][ni], 0, 0, 0);
  }

#pragma unroll
  for (int ni = 0; ni < 4; ++ni) {
    const long gn = colStart + wn + ni * 16 + c15;
    const float bv = bias[gn];
#pragma unroll
    for (int mi = 0; mi < 4; ++mi) {
#pragma unroll
      for (int r = 0; r < 4; ++r) {
        const long gm = rowStart + wm + mi * 16 + quad * 4 + r;
        float v = acc[mi][ni][r] + bv;
        v = fmaxf(v, 0.0f);
        C[gm * HID + gn] = (f16)v;
      }
    }
  }
}

// ---------------------------------------------------------------------------
// FUSED gemm3(layer l) + coupling + gemm1(layer l+1), 64-row strips.
// Phase 1 = R9 gemm3_coupling body (validated). Barrier (drains coupling
// stores; same-CU L2 serves the re-read — A lines never touched L1 earlier
// this dispatch, so no stale-hit risk). Phase 2 = gemm1 with the A-strip
// resident in LDS (gemm1_full's validated stage/swizzle) and B in the
// validated BK=32 1-barrier dbuf, 8 col-tiles x 5 k-steps = 40 steps.
// 512 blocks -> 2 blocks/CU (barrier stagger preserved). LDS 52 KB.
// ---------------------------------------------------------------------------
__global__ __launch_bounds__(256, 2)
void g3g1(const f16* __restrict__ X2, const f16* __restrict__ W3t,
          const float* __restrict__ b3, float* __restrict__ z,
          float* __restrict__ log_det, f16* __restrict__ A,
          const int maskoff,
          const f16* __restrict__ W1n,      // next layer W1t (1024 x 160)
          const float* __restrict__ b1n,    // next layer b1
          f16* __restrict__ X1)
{
  __shared__ __align__(16) f16 As3[2][64 * 32];   // 8 KB
  __shared__ __align__(16) f16 Bs3[2][64 * 32];   // 8 KB
  __shared__ __align__(16) f16 smA[64 * 160];     // 20 KB resident A-strip
  __shared__ __align__(16) f16 smB[2][128 * 32];  // 16 KB B dbuf

  const int tid = threadIdx.x;
  const int wave = tid >> 6, lane = tid & 63;
  const int c15 = lane & 15, quad = lane >> 4;
  const long rowStart = (long)blockIdx.x * 64;

  // ================= phase 1: gemm3 + coupling (R9 body) =================
  {
    const int wm = wave * 16;
    const f16* Ab = X2 + rowStart * HID;
    const int ra  = tid >> 2;
    const int kca = (((tid & 3) ^ ((ra >> 1) & 3))) * 8;

    f32x4 acc[4] = {};

    auto stage = [&](int kt, int sel) {
      const long ko = (long)kt * 32;
      async_copy16(Ab + (long)ra * HID + ko + kca,
                   &As3[sel][0] + (wave * 64) * 8);
      async_copy16(W3t + (long)ra * HID + ko + kca,
                   &Bs3[sel][0] + (wave * 64) * 8);
    };

    stage(0, 0);
    for (int kt = 0; kt < 32; ++kt) {
      __syncthreads();
      if (kt + 1 < 32) stage(kt + 1, (kt + 1) & 1);
      const f16* as = &As3[kt & 1][0];
      const f16* bs = &Bs3[kt & 1][0];

      const int Ra = wm + c15;
      f16x8 a = *(const f16x8*)&as[Ra * 32 + ((quad ^ ((Ra >> 1) & 3)) << 3)];
      f16x8 bf[4];
#pragma unroll
      for (int ni = 0; ni < 4; ++ni) {
        const int R = ni * 16 + c15;
        bf[ni] = *(const f16x8*)&bs[R * 32 + ((quad ^ ((R >> 1) & 3)) << 3)];
      }
#pragma unroll
      for (int ni = 0; ni < 4; ++ni)
        acc[ni] = __builtin_amdgcn_mfma_f32_16x16x32_f16(a, bf[ni], acc[ni], 0, 0, 0);
    }

    float sp[4] = {0.0f, 0.0f, 0.0f, 0.0f};
#pragma unroll
    for (int ni = 0; ni < 2; ++ni) {
      const int j = ni * 16 + c15;          // s-column 0..31
      const float bs = b3[j];
      const float bt = b3[32 + j];
#pragma unroll
      for (int r = 0; r < 4; ++r) {
        const long gm = rowStart + wm + quad * 4 + r;
        const float sv = acc[ni][r] + bs;
        const float e2 = __expf(2.0f * sv);            // tanh via exp
        const float s  = 1.0f - 2.0f / (e2 + 1.0f);
        const float tv = acc[ni + 2][r] + bt;
        const float m  = z[gm * 64 + maskoff + j];
        const float y  = fmaf(m, __expf(s), tv);
        z[gm * 64 + maskoff + j] = y;
        A[gm * AK + j] = (f16)y;       // next layer's unmasked input
        sp[r] += s;
      }
    }
#pragma unroll
    for (int r = 0; r < 4; ++r) {
      float v = sp[r];
      v += __shfl_xor(v, 1);
      v += __shfl_xor(v, 2);
      v += __shfl_xor(v, 4);
      v += __shfl_xor(v, 8);
      if (c15 == 0) {
        const long gm = rowStart + wm + quad * 4 + r;
        log_det[gm] += v;
      }
    }
  }

  __syncthreads();   // drains coupling stores (vmcnt(0)) before A re-read

  // ================= phase 2: gemm1 for the same 64 rows =================
  {
    // stage resident A-strip: 64 x 160 = 1280 chunks, 5 issues of 256.
    // slot f holds global chunk (f%20)^((row>>1)&3) of row f/20 (validated).
#pragma unroll
    for (int it = 0; it < 5; ++it) {
      const int f = it * 256 + tid;
      const int row = f / 20;
      const int ch  = f - row * 20;
      const int chs = ch ^ ((row >> 1) & 3);
      async_copy16(A + (rowStart + row) * AK + chs * 8, &smA[0] + (long)f * 8);
    }

    const int ra  = tid >> 2;
    const int kca = (((tid & 3) ^ ((ra >> 1) & 3))) * 8;
    const int wm1 = (wave & 1) * 32;
    const int wn  = (wave >> 1) * 64;

    auto stageB = [&](int s, int sel) {
      const int ct = s / 5, kt = s - ct * 5;
      const f16* Bb = W1n + (long)(ct * 128) * AK;
#pragma unroll
      for (int q = 0; q < 2; ++q)
        async_copy16(Bb + (long)(q * 64 + ra) * AK + kt * 32 + kca,
                     &smB[sel][0] + (q * 256 + wave * 64) * 8);
    };

    stageB(0, 0);
    f32x4 acc1[2][4] = {};
    for (int s = 0; s < 40; ++s) {
      __syncthreads();                 // drains stage(s) (+A stage at s=0)
      if (s + 1 < 40) stageB(s + 1, (s + 1) & 1);
      const int ct = s / 5, kt = s - ct * 5;
      const f16* bs = &smB[s & 1][0];

      f16x8 a[2], bf[4];
#pragma unroll
      for (int mi = 0; mi < 2; ++mi) {
        const int R = wm1 + mi * 16 + c15;
        a[mi] = *(const f16x8*)&smA[(R * 20 + kt * 4 + (quad ^ ((R >> 1) & 3))) * 8];
      }
#pragma unroll
      for (int ni = 0; ni < 4; ++ni) {
        const int R = wn + ni * 16 + c15;
        bf[ni] = *(const f16x8*)&bs[R * 32 + ((quad ^ ((R >> 1) & 3)) << 3)];
      }
#pragma unroll
      for (int mi = 0; mi < 2; ++mi)
#pragma unroll
        for (int ni = 0; ni < 4; ++ni)
          acc1[mi][ni] = __builtin_amdgcn_mfma_f32_16x16x32_f16(
              a[mi], bf[ni], acc1[mi][ni], 0, 0, 0);

      if (kt == 4) {                   // col-tile done: epilogue + reset
#pragma unroll
        for (int ni = 0; ni < 4; ++ni) {
          const long gn = (long)ct * 128 + wn + ni * 16 + c15;
          const float bv = b1n[gn];
#pragma unroll
          for (int mi = 0; mi < 2; ++mi) {
#pragma unroll
            for (int r = 0; r < 4; ++r) {
              const long gm = rowStart + wm1 + mi * 16 + quad * 4 + r;
              float v = acc1[mi][ni][r] + bv;
              v = fmaxf(v, 0.0f);
              X1[gm * HID + gn] = (f16)v;
              acc1[mi][ni][r] = 0.0f;
            }
          }
        }
      }
    }
  }
}

// ---------------------------------------------------------------------------
// GEMM3 (layer 5 only) + coupling epilogue. R9 version unchanged.
// ---------------------------------------------------------------------------
__global__ __launch_bounds__(256, 4)
void gemm3_coupling(const f16* __restrict__ X2, const f16* __restrict__ W3t,
                    const float* __restrict__ b3, float* __restrict__ z,
                    float* __restrict__ log_det, f16* __restrict__ Anext,
                    const int maskoff)
{
  __shared__ __align__(16) f16 As[2][64 * 32];
  __shared__ __align__(16) f16 Bs[2][64 * 32];
  const int tid = threadIdx.x;
  const int wave = tid >> 6, lane = tid & 63;
  const int c15 = lane & 15, quad = lane >> 4;
  const int wm = wave * 16;
  const long rowStart = (long)blockIdx.x * 64;

  const f16* Ab = X2 + rowStart * HID;
  const int ra  = tid >> 2;
  const int kca = (((tid & 3) ^ ((ra >> 1) & 3))) * 8;

  f32x4 acc[4] = {};

  auto stage = [&](int kt, int sel) {
    const long ko = (long)kt * 32;
    async_copy16(Ab + (long)ra * HID + ko + kca,
                 &As[sel][0] + (wave * 64) * 8);
    async_copy16(W3t + (long)ra * HID + ko + kca,
                 &Bs[sel][0] + (wave * 64) * 8);
  };

  stage(0, 0);
  for (int kt = 0; kt < 32; ++kt) {
    __syncthreads();
    if (kt + 1 < 32) stage(kt + 1, (kt + 1) & 1);
    const f16* as = &As[kt & 1][0];
    const f16* bs = &Bs[kt & 1][0];

    const int Ra = wm + c15;
    f16x8 a = *(const f16x8*)&as[Ra * 32 + ((quad ^ ((Ra >> 1) & 3)) << 3)];
    f16x8 bf[4];
#pragma unroll
    for (int ni = 0; ni < 4; ++ni) {
      const int R = ni * 16 + c15;
      bf[ni] = *(const f16x8*)&bs[R * 32 + ((quad ^ ((R >> 1) & 3)) << 3)];
    }
#pragma unroll
    for (int ni = 0; ni < 4; ++ni)
      acc[ni] = __builtin_amdgcn_mfma_f32_16x16x32_f16(a, bf[ni], acc[ni], 0, 0, 0);
  }

  float sp[4] = {0.0f, 0.0f, 0.0f, 0.0f};
#pragma unroll
  for (int ni = 0; ni < 2; ++ni) {
    const int j = ni * 16 + c15;
    const float bs = b3[j];
    const float bt = b3[32 + j];
#pragma unroll
    for (int r = 0; r < 4; ++r) {
      const long gm = rowStart + wm + quad * 4 + r;
      const float sv = acc[ni][r] + bs;
      const float e2 = __expf(2.0f * sv);
      const float s  = 1.0f - 2.0f / (e2 + 1.0f);
      const float tv = acc[ni + 2][r] + bt;
      const float m  = z[gm * 64 + maskoff + j];
      const float y  = fmaf(m, __expf(s), tv);
      z[gm * 64 + maskoff + j] = y;
      Anext[gm * AK + j] = (f16)y;
      sp[r] += s;
    }
  }
#pragma unroll
  for (int r = 0; r < 4; ++r) {
    float v = sp[r];
    v += __shfl_xor(v, 1);
    v += __shfl_xor(v, 2);
    v += __shfl_xor(v, 4);
    v += __shfl_xor(v, 8);
    if (c15 == 0) {
      const long gm = rowStart + wm + quad * 4 + r;
      log_det[gm] += v;
    }
  }
}

// ---------------------------------------------------------------------------
extern "C" void kernel_launch(void* const* d_in, const int* in_sizes, int n_in,
                              void* d_out, int out_size, void* d_ws, size_t ws_size,
                              hipStream_t stream) {
  (void)in_sizes; (void)n_in; (void)out_size; (void)ws_size;
  const float* T    = (const float*)d_in[0];
  const float* cond = (const float*)d_in[1];
  const float* W1   = (const float*)d_in[2];
  const float* b1   = (const float*)d_in[3];
  const float* W2   = (const float*)d_in[4];
  const float* b2   = (const float*)d_in[5];
  const float* W3   = (const float*)d_in[6];
  const float* b3   = (const float*)d_in[7];

  float* z  = (float*)d_out;                 // B x 64 working state = output
  float* ld = z + (size_t)NB * 64;           // B log_det

  f16* A   = (f16*)d_ws;                     // B x 160
  f16* X1  = A   + (size_t)NB * AK;          // B x 1024
  f16* X2  = X1  + (size_t)NB * HID;         // B x 1024
  f16* W1t = X2  + (size_t)NB * HID;         // 6 x 1024 x 160
  f16* W2t = W1t + (size_t)6 * 1024 * 160;   // 6 x 1024 x 1024
  f16* W3t = W2t + ((size_t)6 << 20);        // 6 x 64 x 1024

  prep_all<<<3968, 256, 0, stream>>>(T, cond, W1, W2, W3,
                                     z, ld, A, W1t, W2t, W3t);

  const int g12 = (NB / 128) * (HID / 128);  // 2048 blocks
  gemm1_full<<<g12, 256, 0, stream>>>(A, W1t, b1, X1);   // layer 0

  for (int l = 0; l < LAYERS; ++l) {
    gemm12<<<g12, 256, 0, stream>>>(X1, HID, W2t + ((size_t)l << 20),
                                    b2 + l * 1024, X2);
    const int maskoff = (l & 1) ? 32 : 0;
    if (l < LAYERS - 1) {
      g3g1<<<NB / 64, 256, 0, stream>>>(
          X2, W3t + (size_t)l * 64 * 1024, b3 + l * 64, z, ld, A, maskoff,
          W1t + (size_t)(l + 1) * 1024 * AK, b1 + (l + 1) * 1024, X1);
    } else {
      gemm3_coupling<<<NB / 64, 256, 0, stream>>>(
          X2, W3t + (size_t)l * 64 * 1024, b3 + l * 64, z, ld, A, maskoff);
    }
  }
}

// Round 13
// 867.858 us; speedup vs baseline: 2.6685x; 1.0203x over previous
//
#include <hip/hip_runtime.h>
#include <hip/hip_fp16.h>
#include <stdint.h>

typedef _Float16 f16;
typedef _Float16 f16x8 __attribute__((ext_vector_type(8)));
typedef float f32x4 __attribute__((ext_vector_type(4)));

#define NB 32768      // batch
#define LAYERS 6
#define AK 160        // HALF + COND
#define HID 1024

// async global->LDS, 16B per lane. LDS dest is wave-uniform base + lane*16.
__device__ __forceinline__ void async_copy16(const void* g, void* l) {
  __builtin_amdgcn_global_load_lds(
      (const __attribute__((address_space(1))) void*)g,
      (__attribute__((address_space(3))) void*)l, 16, 0, 0);
}

// ---------------------------------------------------------------------------
// Fused prep: batch state + 3 weight transposes in one kernel (R9, validated).
// ---------------------------------------------------------------------------
__device__ __forceinline__ void wtrans_tile(const float* __restrict__ W,
                                            f16* __restrict__ Wt,
                                            const int K_, const int N_,
                                            const int bx, const int by,
                                            const int bz, float (*t)[65])
{
  const long off = (long)bz * K_ * N_;
  const float* Wl = W + off;
  f16* Wtl = Wt + off;
  const int k0 = by * 64, n0 = bx * 64;
  const int tx = threadIdx.x & 63, ty4 = threadIdx.x >> 6;
#pragma unroll
  for (int r = ty4; r < 64; r += 4) {
    const int k = k0 + r;
    if (k < K_) t[r][tx] = Wl[(long)k * N_ + n0 + tx];
  }
  __syncthreads();
  const int k = k0 + tx;
  if (k < K_) {
#pragma unroll
    for (int r = ty4; r < 64; r += 4) {
      const int n = n0 + r;
      Wtl[(long)n * K_ + k] = (f16)t[tx][r];
    }
  }
}

__global__ void prep_all(const float* __restrict__ T, const float* __restrict__ cond,
                         const float* __restrict__ W1, const float* __restrict__ W2,
                         const float* __restrict__ W3,
                         float* __restrict__ z, float* __restrict__ ld,
                         f16* __restrict__ A,
                         f16* __restrict__ W1t, f16* __restrict__ W2t,
                         f16* __restrict__ W3t)
{
  __shared__ float t[64][65];
  const int b = blockIdx.x;
  if (b < 2048) {
    const int S1 = NB * 64;
    const int S2 = S1 + NB;
    const int S3 = S2 + NB * 32;
    const int S4 = S3 + NB * 128;
    for (int i = b * blockDim.x + threadIdx.x; i < S4; i += 2048 * blockDim.x) {
      if (i < S1) {
        z[i] = T[i];
      } else if (i < S2) {
        ld[i - S1] = 0.0f;
      } else if (i < S3) {
        int r = i - S2;
        int row = r >> 5, j = r & 31;
        A[(size_t)row * AK + j] = (f16)T[row * 64 + 32 + j];
      } else {
        int r = i - S3;
        int row = r >> 7, j = r & 127;
        A[(size_t)row * AK + 32 + j] = (f16)cond[r];
      }
    }
  } else if (b < 2048 + 288) {
    const int l = b - 2048;                      // 16 x 3 x 6
    wtrans_tile(W1, W1t, AK, 1024, l % 16, (l / 16) % 3, l / 48, t);
  } else if (b < 2048 + 288 + 1536) {
    const int l = b - (2048 + 288);              // 16 x 16 x 6
    wtrans_tile(W2, W2t, HID, 1024, l % 16, (l / 16) % 16, l / 256, t);
  } else {
    const int l = b - (2048 + 288 + 1536);       // 1 x 16 x 6
    wtrans_tile(W3, W3t, HID, 64, 0, l % 16, l / 16, t);
  }
}

// ---------------------------------------------------------------------------
// GEMM1 (K=160): entire 128x160 tiles in 80 KB LDS, one barrier, 80 straight
// MFMA. Validated R8 body, unchanged.
// ---------------------------------------------------------------------------
__global__ __launch_bounds__(256, 2)
void gemm1_full(const f16* __restrict__ A,
                const f16* __restrict__ Wt,       // 1024 x 160
                const float* __restrict__ bias,
                f16* __restrict__ C)
{
  __shared__ __align__(16) f16 As[128 * 160];     // 40 KB
  __shared__ __align__(16) f16 Bs[128 * 160];     // 40 KB
  const int tid  = threadIdx.x;
  const int lane = tid & 63;
  const int wave = tid >> 6;
  const int c15  = lane & 15;
  const int quad = lane >> 4;
  const int wm = (wave & 1) * 64;
  const int wn = (wave >> 1) * 64;

  const int b = blockIdx.x;
  const int x = b & 7, i = b >> 3;
  const long rowStart = (long)(x * 32 + (i >> 3)) * 128;
  const long colStart = (long)(i & 7) * 128;

  const f16* Ab = A  + rowStart * AK;
  const f16* Bb = Wt + colStart * AK;

#pragma unroll
  for (int it = 0; it < 10; ++it) {
    const int f = it * 256 + tid;
    const int row = f / 20;
    const int ch  = f - row * 20;
    const int chs = ch ^ ((row >> 1) & 3);
    async_copy16(Ab + (long)row * AK + chs * 8, &As[0] + (long)f * 8);
    async_copy16(Bb + (long)row * AK + chs * 8, &Bs[0] + (long)f * 8);
  }
  __syncthreads();

  f32x4 acc[4][4] = {};
#pragma unroll
  for (int kt = 0; kt < 5; ++kt) {
    f16x8 a[4], bf[4];
#pragma unroll
    for (int mi = 0; mi < 4; ++mi) {
      const int R = wm + mi * 16 + c15;
      a[mi] = *(const f16x8*)&As[(R * 20 + kt * 4 + (quad ^ ((R >> 1) & 3))) * 8];
    }
#pragma unroll
    for (int ni = 0; ni < 4; ++ni) {
      const int R = wn + ni * 16 + c15;
      bf[ni] = *(const f16x8*)&Bs[(R * 20 + kt * 4 + (quad ^ ((R >> 1) & 3))) * 8];
    }
#pragma unroll
    for (int mi = 0; mi < 4; ++mi)
#pragma unroll
      for (int ni = 0; ni < 4; ++ni)
        acc[mi][ni] = __builtin_amdgcn_mfma_f32_16x16x32_f16(
            a[mi], bf[ni], acc[mi][ni], 0, 0, 0);
  }

#pragma unroll
  for (int ni = 0; ni < 4; ++ni) {
    const long gn = colStart + wn + ni * 16 + c15;
    const float bv = bias[gn];
#pragma unroll
    for (int mi = 0; mi < 4; ++mi) {
#pragma unroll
      for (int r = 0; r < 4; ++r) {
        const long gm = rowStart + wm + mi * 16 + quad * 4 + r;
        float v = acc[mi][ni][r] + bv;
        v = fmaxf(v, 0.0f);
        C[gm * HID + gn] = (f16)v;
      }
    }
  }
}

// ---------------------------------------------------------------------------
// GEMM2 (K=1024): the plateau kernel, unchanged (structural ceiling ~88 us
// verified R3/R7/R9/R12; all restructurings R4/R5/R6/R10/R11 regressed).
// ---------------------------------------------------------------------------
__global__ __launch_bounds__(256, 3)
void gemm12(const f16* __restrict__ A, const int K,
            const f16* __restrict__ Wt,
            const float* __restrict__ bias,
            f16* __restrict__ C)
{
  __shared__ __align__(16) f16 As[2][128 * 32];
  __shared__ __align__(16) f16 Bs[2][128 * 32];
  const int tid  = threadIdx.x;
  const int wave = tid >> 6;
  const int lane = tid & 63;
  const int c15  = lane & 15;
  const int quad = lane >> 4;
  const int wm = (wave & 1) * 64;
  const int wn = (wave >> 1) * 64;

  const int b = blockIdx.x;
  const int x = b & 7, i = b >> 3;
  const long rowStart = (long)(x * 32 + (i >> 3)) * 128;
  const long colStart = (long)(i & 7) * 128;

  const f16* Ab = A  + rowStart * K;
  const f16* Bb = Wt + colStart * K;

  const int ra  = tid >> 2;
  const int kca = (((tid & 3) ^ ((ra >> 1) & 3))) * 8;

  f32x4 acc[4][4] = {};
  const int nK = K >> 5;

  auto stage = [&](int kt, int sel) {
    const long ko = (long)kt * 32;
    f16* as = &As[sel][0];
    f16* bs = &Bs[sel][0];
#pragma unroll
    for (int q = 0; q < 2; ++q)
      async_copy16(Ab + (long)(q * 64 + ra) * K + ko + kca,
                   as + (q * 256 + wave * 64) * 8);
#pragma unroll
    for (int q = 0; q < 2; ++q)
      async_copy16(Bb + (long)(q * 64 + ra) * K + ko + kca,
                   bs + (q * 256 + wave * 64) * 8);
  };

  stage(0, 0);
  for (int kt = 0; kt < nK; ++kt) {
    __syncthreads();
    if (kt + 1 < nK) stage(kt + 1, (kt + 1) & 1);
    const f16* as = &As[kt & 1][0];
    const f16* bs = &Bs[kt & 1][0];

    f16x8 a[4], bf[4];
#pragma unroll
    for (int mi = 0; mi < 4; ++mi) {
      const int R = wm + mi * 16 + c15;
      a[mi] = *(const f16x8*)&as[R * 32 + ((quad ^ ((R >> 1) & 3)) << 3)];
    }
#pragma unroll
    for (int ni = 0; ni < 4; ++ni) {
      const int R = wn + ni * 16 + c15;
      bf[ni] = *(const f16x8*)&bs[R * 32 + ((quad ^ ((R >> 1) & 3)) << 3)];
    }
#pragma unroll
    for (int mi = 0; mi < 4; ++mi)
#pragma unroll
      for (int ni = 0; ni < 4; ++ni)
        acc[mi][ni] = __builtin_amdgcn_mfma_f32_16x16x32_f16(
            a[mi], bf[ni], acc[mi][ni], 0, 0, 0);
  }

#pragma unroll
  for (int ni = 0; ni < 4; ++ni) {
    const long gn = colStart + wn + ni * 16 + c15;
    const float bv = bias[gn];
#pragma unroll
    for (int mi = 0; mi < 4; ++mi) {
#pragma unroll
      for (int r = 0; r < 4; ++r) {
        const long gm = rowStart + wm + mi * 16 + quad * 4 + r;
        float v = acc[mi][ni][r] + bv;
        v = fmaxf(v, 0.0f);
        C[gm * HID + gn] = (f16)v;
      }
    }
  }
}

// ---------------------------------------------------------------------------
// GEMM3 (N=64) + coupling epilogue — R13: BK=64 chunks (16 barriers instead
// of 32; the kernel is the most drain-bound of the set: 4 MFMA/wave-step vs
// a ~300-600 cyc drain at BK=32). Staging geometry = R6's validated
// conflict-free pattern (measured SQ_LDS_BANK_CONFLICT=0): slot f=q*256+tid
// holds logical chunk (tid&7)^(row&7) of row q*32+(tid>>3); reads at phys
// chunk (s*4+quad)^(R&7). LDS 32 KB dbuf; grid 512 -> 2 blocks/CU.
// s-col j and t-col j+32 share lane & reg slot -> no shuffles.
// ---------------------------------------------------------------------------
__global__ __launch_bounds__(256, 2)
void gemm3_coupling(const f16* __restrict__ X2, const f16* __restrict__ W3t,
                    const float* __restrict__ b3, float* __restrict__ z,
                    float* __restrict__ log_det, f16* __restrict__ Anext,
                    const int maskoff)
{
  __shared__ __align__(16) f16 As[2][64 * 64];    // 8 KB per buffer
  __shared__ __align__(16) f16 Bs[2][64 * 64];
  const int tid = threadIdx.x;
  const int wave = tid >> 6, lane = tid & 63;
  const int c15 = lane & 15, quad = lane >> 4;
  const int wm = wave * 16;
  const long rowStart = (long)blockIdx.x * 64;

  const f16* Ab = X2 + rowStart * HID;
  const int brow = tid >> 3;                       // 0..31 (+q*32)
  const int bkc  = ((tid & 7) ^ (brow & 7)) * 8;

  f32x4 acc[4] = {};

  auto stage = [&](int c, int sel) {
    const long kb = (long)c * 64;
#pragma unroll
    for (int q = 0; q < 2; ++q) {
      async_copy16(Ab  + (long)(q * 32 + brow) * HID + kb + bkc,
                   &As[sel][0] + (q * 256 + wave * 64) * 8);
      async_copy16(W3t + (long)(q * 32 + brow) * HID + kb + bkc,
                   &Bs[sel][0] + (q * 256 + wave * 64) * 8);
    }
  };

  stage(0, 0);
  for (int c = 0; c < 16; ++c) {
    __syncthreads();                 // drains stage(c), issued one step ago
    if (c + 1 < 16) stage(c + 1, (c + 1) & 1);
    const f16* as = &As[c & 1][0];
    const f16* bs = &Bs[c & 1][0];

#pragma unroll
    for (int s = 0; s < 2; ++s) {
      const int Ra = wm + c15;
      f16x8 a = *(const f16x8*)&as[(Ra * 8 + ((s * 4 + quad) ^ (Ra & 7))) * 8];
      f16x8 bf[4];
#pragma unroll
      for (int ni = 0; ni < 4; ++ni) {
        const int R = ni * 16 + c15;
        bf[ni] = *(const f16x8*)&bs[(R * 8 + ((s * 4 + quad) ^ (R & 7))) * 8];
      }
#pragma unroll
      for (int ni = 0; ni < 4; ++ni)
        acc[ni] = __builtin_amdgcn_mfma_f32_16x16x32_f16(a, bf[ni], acc[ni], 0, 0, 0);
    }
  }

  float sp[4] = {0.0f, 0.0f, 0.0f, 0.0f};
#pragma unroll
  for (int ni = 0; ni < 2; ++ni) {
    const int j = ni * 16 + c15;          // s-column 0..31
    const float bs = b3[j];
    const float bt = b3[32 + j];
#pragma unroll
    for (int r = 0; r < 4; ++r) {
      const long gm = rowStart + wm + quad * 4 + r;
      const float sv = acc[ni][r] + bs;
      const float e2 = __expf(2.0f * sv);            // tanh via exp
      const float s  = 1.0f - 2.0f / (e2 + 1.0f);
      const float tv = acc[ni + 2][r] + bt;
      const float m  = z[gm * 64 + maskoff + j];
      const float y  = fmaf(m, __expf(s), tv);
      z[gm * 64 + maskoff + j] = y;
      Anext[gm * AK + j] = (f16)y;   // next layer's unmasked input
      sp[r] += s;
    }
  }
#pragma unroll
  for (int r = 0; r < 4; ++r) {
    float v = sp[r];
    v += __shfl_xor(v, 1);
    v += __shfl_xor(v, 2);
    v += __shfl_xor(v, 4);
    v += __shfl_xor(v, 8);
    if (c15 == 0) {
      const long gm = rowStart + wm + quad * 4 + r;
      log_det[gm] += v;   // only this thread touches this row this layer
    }
  }
}

// ---------------------------------------------------------------------------
extern "C" void kernel_launch(void* const* d_in, const int* in_sizes, int n_in,
                              void* d_out, int out_size, void* d_ws, size_t ws_size,
                              hipStream_t stream) {
  (void)in_sizes; (void)n_in; (void)out_size; (void)ws_size;
  const float* T    = (const float*)d_in[0];
  const float* cond = (const float*)d_in[1];
  const float* W1   = (const float*)d_in[2];
  const float* b1   = (const float*)d_in[3];
  const float* W2   = (const float*)d_in[4];
  const float* b2   = (const float*)d_in[5];
  const float* W3   = (const float*)d_in[6];
  const float* b3   = (const float*)d_in[7];

  float* z  = (float*)d_out;                 // B x 64 working state = output
  float* ld = z + (size_t)NB * 64;           // B log_det

  f16* A   = (f16*)d_ws;                     // B x 160
  f16* X1  = A   + (size_t)NB * AK;          // B x 1024
  f16* X2  = X1  + (size_t)NB * HID;         // B x 1024
  f16* W1t = X2  + (size_t)NB * HID;         // 6 x 1024 x 160
  f16* W2t = W1t + (size_t)6 * 1024 * 160;   // 6 x 1024 x 1024
  f16* W3t = W2t + ((size_t)6 << 20);        // 6 x 64 x 1024

  prep_all<<<3968, 256, 0, stream>>>(T, cond, W1, W2, W3,
                                     z, ld, A, W1t, W2t, W3t);

  const int g12 = (NB / 128) * (HID / 128);  // 2048 blocks
  for (int l = 0; l < LAYERS; ++l) {
    gemm1_full<<<g12, 256, 0, stream>>>(A, W1t + (size_t)l * 1024 * AK,
                                        b1 + l * 1024, X1);
    gemm12<<<g12, 256, 0, stream>>>(X1, HID, W2t + ((size_t)l << 20),
                                    b2 + l * 1024, X2);
    const int maskoff = (l & 1) ? 32 : 0;
    gemm3_coupling<<<NB / 64, 256, 0, stream>>>(X2, W3t + (size_t)l * 64 * 1024,
                                                b3 + l * 64, z, ld, A, maskoff);
  }
}